// Round 14
// baseline (424.043 us; speedup 1.0000x reference)
//
#include <hip/hip_runtime.h>

#define N_NODES 100000
#define N_EDGES 1600000
#define NF 128
#define NC 16
#define NH 2
#define HC 32   // NH*NC
#define NL 2
#define NED 4
#define EPS 1e-5f
#define NEG 0.2f
#define NBUCK 196                    // ceil(N_NODES / 512)
#define P1_CHUNK 8192
#define P1_BLKS ((N_EDGES + P1_CHUNK - 1) / P1_CHUNK)   // 196
#define AGG_BLKS ((N_NODES + 31) / 32)             // 3125  (32 dst/block, 8 lanes/dst)
#define MID_BLKS ((N_NODES + 15) / 16)             // 6250

typedef __attribute__((ext_vector_type(2))) float f32x2;

// ---- bf16 helpers (manual, RTN-even) -----------------------------------------
__device__ __forceinline__ unsigned short f2bf(float f) {
    unsigned int u = __float_as_uint(f);
    u += 0x7fffu + ((u >> 16) & 1u);
    return (unsigned short)(u >> 16);
}
__device__ __forceinline__ float bf2f(unsigned short u) {
    return __uint_as_float(((unsigned int)u) << 16);
}
__device__ __forceinline__ unsigned int pack_bf2(float a, float b) {
    return (unsigned int)f2bf(a) | ((unsigned int)f2bf(b) << 16);
}
__device__ __forceinline__ float bflo(int u) {
    return __uint_as_float(((unsigned int)u) << 16);
}
__device__ __forceinline__ float bfhi(int u) {
    return __uint_as_float(((unsigned int)u) & 0xffff0000u);
}
__device__ __forceinline__ f32x2 sp2(float v) { f32x2 r; r.x = v; r.y = v; return r; }
// 8-byte load helper: 4 adjacent bf16 channels (packed in int2) -> 2x f32x2
__device__ __forceinline__ void bf4_unpack(int2 v, f32x2& p01, f32x2& p23) {
    p01.x = bflo(v.x); p01.y = bfhi(v.x);
    p23.x = bflo(v.y); p23.y = bfhi(v.y);
}
__device__ __forceinline__ int2 ld8(const unsigned short* base, unsigned boff) {
    return *(const int2*)((const char*)base + boff);
}

// ---- embed + layer-0 transforms fused ----------------------------------------
// h = relu(node_LN(x @ W + b)); jk = h; xl/xr = bf16(h @ Wl + bl, h @ Wr + br)
__global__ __launch_bounds__(256) void k_embed(
    const float* __restrict__ x, const float* __restrict__ W,
    const float* __restrict__ b, const float* __restrict__ lnw,
    const float* __restrict__ lnb,
    const float* __restrict__ Wl, const float* __restrict__ bl,
    const float* __restrict__ Wr, const float* __restrict__ br,
    float* __restrict__ h, float* __restrict__ jk,
    unsigned short* __restrict__ xl, unsigned short* __restrict__ xr)
{
    __shared__ __align__(16) float WsT[NC][NF + 4];   // [c][f]
    __shared__ __align__(16) float xs[16][NF + 4];
    __shared__ float Wls[NC * HC], Wrs[NC * HC];
    __shared__ float hs16[16][NC + 1];
    const int t = threadIdx.x;
    for (int i = t; i < NF * NC; i += 256) {
        int f = i >> 4, c = i & 15;
        WsT[c][f] = W[i];
    }
    for (int i = t; i < NC * HC; i += 256) { Wls[i] = Wl[i]; Wrs[i] = Wr[i]; }
    const int n0 = blockIdx.x * 16;
    const float4* x4 = (const float4*)x;
    for (int i = t; i < 16 * (NF / 4); i += 256) {    // 512 float4
        int r = i >> 5, f4 = i & 31;
        int n = n0 + r;
        float4 v = (n < N_NODES) ? x4[(size_t)n * (NF / 4) + f4]
                                 : make_float4(0.f, 0.f, 0.f, 0.f);
        *(float4*)&xs[r][f4 * 4] = v;
    }
    __syncthreads();
    const int r = t >> 4;
    const int c = t & 15;
    const int n = n0 + r;
    float acc = b[c];
#pragma unroll
    for (int f4 = 0; f4 < NF / 4; ++f4) {
        float4 xv = *(const float4*)&xs[r][f4 * 4];
        float4 wv = *(const float4*)&WsT[c][f4 * 4];
        acc += xv.x * wv.x + xv.y * wv.y + xv.z * wv.z + xv.w * wv.w;
    }
    float s = acc;
    for (int m = 8; m >= 1; m >>= 1) s += __shfl_xor(s, m, 16);
    float mu = s * (1.f / 16.f);
    float d = acc - mu;
    float v = d * d;
    for (int m = 8; m >= 1; m >>= 1) v += __shfl_xor(v, m, 16);
    float inv = rsqrtf(v * (1.f / 16.f) + EPS);
    float out = fmaxf(d * inv * lnw[c] + lnb[c], 0.f);
    if (n < N_NODES) {
        h[(size_t)n * NC + c]  = out;
        jk[(size_t)n * NC + c] = out;
    }
    hs16[r][c] = (n < N_NODES) ? out : 0.f;
    __syncthreads();
    // layer-0 transforms: lane c covers channels j=c and j=c+16
    float al0 = bl[c], al1 = bl[c + 16];
    float ar0 = br[c], ar1 = br[c + 16];
#pragma unroll
    for (int cc = 0; cc < NC; ++cc) {
        float hv = hs16[r][cc];
        al0 += hv * Wls[cc * HC + c];      al1 += hv * Wls[cc * HC + c + 16];
        ar0 += hv * Wrs[cc * HC + c];      ar1 += hv * Wrs[cc * HC + c + 16];
    }
    if (n < N_NODES) {
        xl[(size_t)n * HC + c]      = f2bf(al0);
        xl[(size_t)n * HC + c + 16] = f2bf(al1);
        xr[(size_t)n * HC + c]      = f2bf(ar0);
        xr[(size_t)n * HC + c + 16] = f2bf(ar1);
    }
}

// ---- bucket histogram (bucket = dst >> 9), LDS-staged ------------------------
__global__ __launch_bounds__(256) void k_bhist(
    const int* __restrict__ dst, int* __restrict__ bcnt)
{
    __shared__ int hist[256];
    const int t = threadIdx.x;
    hist[t] = 0;
    __syncthreads();
    const int e0 = blockIdx.x * P1_CHUNK;
    const int cnt = min(P1_CHUNK, N_EDGES - e0);
    for (int i = t; i < cnt; i += 256)
        atomicAdd(&hist[dst[e0 + i] >> 9], 1);
    __syncthreads();
    if (hist[t] > 0) atomicAdd(&bcnt[t], hist[t]);
}

// ---- scan 196 bucket counts -> bases + working cursors -----------------------
__global__ __launch_bounds__(256) void k_bscan(
    const int* __restrict__ bcnt, int* __restrict__ bbase, int* __restrict__ bcur)
{
    __shared__ int tmp[256];
    const int t = threadIdx.x;
    int v0 = bcnt[t];
    tmp[t] = v0;
    __syncthreads();
    for (int off = 1; off < 256; off <<= 1) {
        int v = (t >= off) ? tmp[t - off] : 0;
        __syncthreads();
        tmp[t] += v;
        __syncthreads();
    }
    int excl = tmp[t] - v0;
    bbase[t] = excl;
    bcur[t]  = excl;
    if (t == 255) bbase[256] = tmp[t];   // == N_EDGES
}

// ---- pass1: no staging, no scan; 8192-edge chunks halve bcur atomic chains ---
__global__ __launch_bounds__(256) void k_pass1(
    const int* __restrict__ src, const int* __restrict__ dst,
    const float4* __restrict__ ea4, int* __restrict__ bcur,
    int4* __restrict__ tmp_rec)
{
    __shared__ int hist[256];
    __shared__ int gbase[256];
    __shared__ int lcur[256];
    const int t = threadIdx.x;
    const int e0 = blockIdx.x * P1_CHUNK;
    const int cnt = min(P1_CHUNK, N_EDGES - e0);
    hist[t] = 0; lcur[t] = 0;
    __syncthreads();
    for (int i = t; i < cnt; i += 256)
        atomicAdd(&hist[dst[e0 + i] >> 9], 1);
    __syncthreads();
    {
        int c = hist[t];
        gbase[t] = (c > 0) ? atomicAdd(&bcur[t], c) : 0;
    }
    __syncthreads();
    for (int i = t; i < cnt; i += 256) {
        int e = e0 + i;
        int d = dst[e];                 // second read: 32KB window, L1/L2 hit
        int s = src[e];
        float4 ea = ea4[e];
        int b = d >> 9;
        int lpos = atomicAdd(&lcur[b], 1);
        tmp_rec[gbase[b] + lpos] = make_int4(s, d,
                                             (int)pack_bf2(ea.x, ea.y),
                                             (int)pack_bf2(ea.z, ea.w));
    }
}

// ---- pass2: one 512-thread block per bucket; per-dst hist+scan -> CSR --------
__global__ __launch_bounds__(512) void k_pass2(
    const int* __restrict__ bbase, const int4* __restrict__ tmp_rec,
    int* __restrict__ offsets, int4* __restrict__ csr)
{
    __shared__ int hist[512];
    __shared__ int cur[512];
    __shared__ int scanbuf[256];
    const int b = blockIdx.x, t = threadIdx.x;
    const int ebeg = bbase[b], eend = bbase[b + 1];
    hist[t] = 0;
    __syncthreads();
    for (int i = ebeg + t; i < eend; i += 512)
        atomicAdd(&hist[tmp_rec[i].y & 511], 1);
    __syncthreads();
    int a0 = 0, a1 = 0, pair = 0;
    if (t < 256) {
        a0 = hist[2 * t]; a1 = hist[2 * t + 1];
        pair = a0 + a1;
        scanbuf[t] = pair;
    }
    __syncthreads();
    for (int off = 1; off < 256; off <<= 1) {
        int v = (t < 256 && t >= off) ? scanbuf[t - off] : 0;
        __syncthreads();
        if (t < 256) scanbuf[t] += v;
        __syncthreads();
    }
    if (t < 256) {
        int ex2 = scanbuf[t] - pair;
        cur[2 * t]     = ex2;
        cur[2 * t + 1] = ex2 + a0;
    }
    __syncthreads();
    {
        int n = b * 512 + t;
        if (n < N_NODES) offsets[n] = ebeg + cur[t];
        if (b == NBUCK - 1 && t == 0) offsets[N_NODES] = N_EDGES;
    }
    __syncthreads();
    // permute (writes stay inside this bucket's L2-resident window)
    for (int i = ebeg + t; i < eend; i += 512) {
        int4 rec = tmp_rec[i];
        int pos = ebeg + atomicAdd(&cur[rec.y & 511], 1);
        csr[pos] = rec;   // {src, d(unused later), eab01, eab23}
    }
}

// per-edge compute macro pieces for k_agg (8 lanes/dst, 4 channels/lane)
#define EDGE_MSG(RA, RB, RZ, RW)                                              \
    RA += sp2(bflo(RZ)) * w0a; RB += sp2(bflo(RZ)) * w0b;                     \
    RA += sp2(bfhi(RZ)) * w1a; RB += sp2(bfhi(RZ)) * w1b;                     \
    RA += sp2(bflo(RW)) * w2a; RB += sp2(bflo(RW)) * w2b;                     \
    RA += sp2(bfhi(RW)) * w3a; RB += sp2(bfhi(RW)) * w3b;                     \
    RA.x = fmaxf(RA.x, NEG * RA.x); RA.y = fmaxf(RA.y, NEG * RA.y);           \
    RB.x = fmaxf(RB.x, NEG * RB.x); RB.y = fmaxf(RB.y, NEG * RB.y);

// ---- aggregation: 8 lanes/dst, 4 channels/lane, unroll-4 (R10-proven) --------
__global__ __launch_bounds__(256) void k_agg(
    const int* __restrict__ offsets, const int4* __restrict__ csr,
    const float* __restrict__ We, const float* __restrict__ att,
    const float* __restrict__ gat_b,
    const unsigned short* __restrict__ xl, const unsigned short* __restrict__ xr,
    float* __restrict__ g, float2* __restrict__ part)
{
    __shared__ float Wes[NED * HC];
    __shared__ float atts[HC], gbs[HC];
    const int t = threadIdx.x;
    if (t < NED * HC) Wes[t] = We[t];
    if (t < HC) { atts[t] = att[t]; gbs[t] = gat_b[t]; }
    __syncthreads();
    const int grp = t >> 3;          // 32 groups of 8 lanes
    const int l   = t & 7;           // channels 4l..4l+3 ; head = l>>2
    const int d = blockIdx.x * 32 + grp;
    f32x2 gv01 = sp2(0.f), gv23 = sp2(0.f);
    if (d < N_NODES) {
        const int c0 = l << 2;
        f32x2 a01; a01.x = atts[c0];     a01.y = atts[c0 + 1];
        f32x2 a23; a23.x = atts[c0 + 2]; a23.y = atts[c0 + 3];
        f32x2 w0a, w0b, w1a, w1b, w2a, w2b, w3a, w3b;
        w0a.x = Wes[c0];          w0a.y = Wes[c0 + 1];
        w0b.x = Wes[c0 + 2];      w0b.y = Wes[c0 + 3];
        w1a.x = Wes[HC + c0];     w1a.y = Wes[HC + c0 + 1];
        w1b.x = Wes[HC + c0 + 2]; w1b.y = Wes[HC + c0 + 3];
        w2a.x = Wes[2 * HC + c0];     w2a.y = Wes[2 * HC + c0 + 1];
        w2b.x = Wes[2 * HC + c0 + 2]; w2b.y = Wes[2 * HC + c0 + 3];
        w3a.x = Wes[3 * HC + c0];     w3a.y = Wes[3 * HC + c0 + 1];
        w3b.x = Wes[3 * HC + c0 + 2]; w3b.y = Wes[3 * HC + c0 + 3];
        const unsigned jb = (unsigned)(l << 3);     // byte offset of channel quad
        f32x2 xld01, xld23, xrd01, xrd23;
        bf4_unpack(ld8(xl, ((unsigned)d << 6) + jb), xld01, xld23);
        bf4_unpack(ld8(xr, ((unsigned)d << 6) + jb), xrd01, xrd23);
        // self-loop (ew = 0); logits tiny: exp without segment-max is exact enough
        f32x2 m01 = xld01 + xrd01, m23 = xld23 + xrd23;
        m01.x = fmaxf(m01.x, NEG * m01.x); m01.y = fmaxf(m01.y, NEG * m01.y);
        m23.x = fmaxf(m23.x, NEG * m23.x); m23.y = fmaxf(m23.y, NEG * m23.y);
        float p = m01.x * a01.x + m01.y * a01.y + m23.x * a23.x + m23.y * a23.y;
        p += __shfl_xor(p, 1);           // quad-perm DPP
        p += __shfl_xor(p, 2);           // quad-perm DPP
        float eh = __expf(p);
        f32x2 acc01 = sp2(eh) * xld01, acc23 = sp2(eh) * xld23;
        float den = eh;
        const int base = offsets[d];
        const int deg  = offsets[d + 1] - base;
        int k = 0;
        for (; k + 4 <= deg; k += 4) {
            const int b0 = base + k;
            const int4 r0 = csr[b0],     r1 = csr[b0 + 1];
            const int4 r2 = csr[b0 + 2], r3 = csr[b0 + 3];
            const int2 v0 = ld8(xl, ((unsigned)r0.x << 6) + jb);
            const int2 v1 = ld8(xl, ((unsigned)r1.x << 6) + jb);
            const int2 v2 = ld8(xl, ((unsigned)r2.x << 6) + jb);
            const int2 v3 = ld8(xl, ((unsigned)r3.x << 6) + jb);
            f32x2 x0a, x0b, x1a, x1b, x2a, x2b, x3a, x3b;
            bf4_unpack(v0, x0a, x0b); bf4_unpack(v1, x1a, x1b);
            bf4_unpack(v2, x2a, x2b); bf4_unpack(v3, x3a, x3b);
            f32x2 m0a = x0a + xrd01, m0b = x0b + xrd23;
            f32x2 m1a = x1a + xrd01, m1b = x1b + xrd23;
            f32x2 m2a = x2a + xrd01, m2b = x2b + xrd23;
            f32x2 m3a = x3a + xrd01, m3b = x3b + xrd23;
            EDGE_MSG(m0a, m0b, r0.z, r0.w)
            EDGE_MSG(m1a, m1b, r1.z, r1.w)
            EDGE_MSG(m2a, m2b, r2.z, r2.w)
            EDGE_MSG(m3a, m3b, r3.z, r3.w)
            float p0 = m0a.x * a01.x + m0a.y * a01.y + m0b.x * a23.x + m0b.y * a23.y;
            float p1 = m1a.x * a01.x + m1a.y * a01.y + m1b.x * a23.x + m1b.y * a23.y;
            float p2 = m2a.x * a01.x + m2a.y * a01.y + m2b.x * a23.x + m2b.y * a23.y;
            float p3 = m3a.x * a01.x + m3a.y * a01.y + m3b.x * a23.x + m3b.y * a23.y;
            p0 += __shfl_xor(p0, 1); p1 += __shfl_xor(p1, 1);
            p2 += __shfl_xor(p2, 1); p3 += __shfl_xor(p3, 1);
            p0 += __shfl_xor(p0, 2); p1 += __shfl_xor(p1, 2);
            p2 += __shfl_xor(p2, 2); p3 += __shfl_xor(p3, 2);
            const float ee0 = __expf(p0), ee1 = __expf(p1);
            const float ee2 = __expf(p2), ee3 = __expf(p3);
            acc01 += sp2(ee0) * x0a; acc23 += sp2(ee0) * x0b;
            acc01 += sp2(ee1) * x1a; acc23 += sp2(ee1) * x1b;
            acc01 += sp2(ee2) * x2a; acc23 += sp2(ee2) * x2b;
            acc01 += sp2(ee3) * x3a; acc23 += sp2(ee3) * x3b;
            den += ee0 + ee1 + ee2 + ee3;
        }
        for (; k < deg; ++k) {
            const int4 r = csr[base + k];
            f32x2 xa, xb;
            bf4_unpack(ld8(xl, ((unsigned)r.x << 6) + jb), xa, xb);
            f32x2 ma = xa + xrd01, mb = xb + xrd23;
            EDGE_MSG(ma, mb, r.z, r.w)
            float p = ma.x * a01.x + ma.y * a01.y + mb.x * a23.x + mb.y * a23.y;
            p += __shfl_xor(p, 1);
            p += __shfl_xor(p, 2);
            const float ee = __expf(p);
            acc01 += sp2(ee) * xa; acc23 += sp2(ee) * xb;
            den += ee;
        }
        const float invd = 1.f / den;
        gv01.x = acc01.x * invd + gbs[c0];
        gv01.y = acc01.y * invd + gbs[c0 + 1];
        gv23.x = acc23.x * invd + gbs[c0 + 2];
        gv23.y = acc23.y * invd + gbs[c0 + 3];
        float4 wv; wv.x = gv01.x; wv.y = gv01.y; wv.z = gv23.x; wv.w = gv23.y;
        *(float4*)&g[(size_t)d * HC + c0] = wv;
    }
    float s  = gv01.x + gv01.y + gv23.x + gv23.y;
    float ss = gv01.x * gv01.x + gv01.y * gv01.y + gv23.x * gv23.x + gv23.y * gv23.y;
    for (int m = 32; m >= 1; m >>= 1) { s += __shfl_xor(s, m); ss += __shfl_xor(ss, m); }
    __shared__ float sr[4], ssr[4];
    const int w = t >> 6;
    if ((t & 63) == 0) { sr[w] = s; ssr[w] = ss; }
    __syncthreads();
    if (t == 0) part[blockIdx.x] = make_float2(sr[0] + sr[1] + sr[2] + sr[3],
                                               ssr[0] + ssr[1] + ssr[2] + ssr[3]);
}

// ---- reduce block partials -> stats[0..1] ------------------------------------
__global__ __launch_bounds__(256) void k_red(
    const float2* __restrict__ part, int n, double* __restrict__ out)
{
    const int t = threadIdx.x;
    double s = 0.0, ss = 0.0;
    for (int i = t; i < n; i += 256) {
        float2 p = part[i];
        s += (double)p.x; ss += (double)p.y;
    }
    for (int m = 32; m >= 1; m >>= 1) { s += __shfl_xor(s, m); ss += __shfl_xor(ss, m); }
    __shared__ double sr[4], ssr[4];
    const int w = t >> 6;
    if ((t & 63) == 0) { sr[w] = s; ssr[w] = ss; }
    __syncthreads();
    if (t == 0) {
        out[0] = sr[0] + sr[1] + sr[2] + sr[3];
        out[1] = ssr[0] + ssr[1] + ssr[2] + ssr[3];
    }
}

// ---- apply LN1 + relu + linear(32->16) + partial stats for LN2 ---------------
__global__ __launch_bounds__(256) void k_mid(
    const float* __restrict__ g,
    const float* __restrict__ n1w, const float* __restrict__ n1b,
    const float* __restrict__ linW, const float* __restrict__ linb,
    const double* __restrict__ stats1, float* __restrict__ g2,
    float2* __restrict__ part)
{
    __shared__ float Ws[HC * NC];
    __shared__ float rs[16][HC + 1];
    const int t = threadIdx.x;
    for (int i = t; i < HC * NC; i += 256) Ws[i] = linW[i];
    const double cnt = (double)N_NODES * HC;
    const double mud = stats1[0] / cnt;
    const float mu  = (float)mud;
    const float var = (float)(stats1[1] / cnt - mud * mud);
    const float inv = rsqrtf(var + EPS);
    const int n0 = blockIdx.x * 16;
    for (int i = t; i < 16 * HC; i += 256) {
        int r = i >> 5, j = i & 31;
        int n = n0 + r;
        float v = (n < N_NODES) ? g[(size_t)n * HC + j] : mu;
        v = (v - mu) * inv * n1w[j] + n1b[j];
        rs[r][j] = fmaxf(v, 0.f);
    }
    __syncthreads();
    const int r = t >> 4, c = t & 15;
    const int n = n0 + r;
    float acc = linb[c];
#pragma unroll
    for (int j = 0; j < HC; ++j) acc += rs[r][j] * Ws[j * NC + c];
    float val = (n < N_NODES) ? acc : 0.f;
    if (n < N_NODES) g2[(size_t)n * NC + c] = acc;
    float s = val, ss = val * val;
    for (int m = 32; m >= 1; m >>= 1) { s += __shfl_xor(s, m); ss += __shfl_xor(ss, m); }
    __shared__ float sr[4], ssr[4];
    const int w = t >> 6;
    if ((t & 63) == 0) { sr[w] = s; ssr[w] = ss; }
    __syncthreads();
    if (t == 0) part[blockIdx.x] = make_float2(sr[0] + sr[1] + sr[2] + sr[3],
                                               ssr[0] + ssr[1] + ssr[2] + ssr[3]);
}

// ---- fused: apply LN2 + residual + relu + jk-max, then next-layer transforms -
__global__ __launch_bounds__(256) void k_ftrans(
    const float* __restrict__ g2, const float* __restrict__ n2w,
    const float* __restrict__ n2b, const double* __restrict__ stats2,
    float* __restrict__ h, float* __restrict__ jk,
    const float* __restrict__ Wl, const float* __restrict__ bl,
    const float* __restrict__ Wr, const float* __restrict__ br,
    unsigned short* __restrict__ xl, unsigned short* __restrict__ xr)
{
    __shared__ float Wls[NC * HC], Wrs[NC * HC];
    __shared__ float hs[8][NC + 1];
    const int t = threadIdx.x;
    for (int i = t; i < NC * HC; i += 256) { Wls[i] = Wl[i]; Wrs[i] = Wr[i]; }
    const double cnt = (double)N_NODES * NC;
    const double mud = stats2[0] / cnt;
    const float mu  = (float)mud;
    const float var = (float)(stats2[1] / cnt - mud * mud);
    const float inv = rsqrtf(var + EPS);
    const int n0 = blockIdx.x * 8;
    if (t < 8 * NC) {
        int r = t >> 4, c = t & 15;
        int n = n0 + r;
        if (n < N_NODES) {
            size_t idx = (size_t)n * NC + c;
            float v = (g2[idx] - mu) * inv * n2w[c] + n2b[c];
            float hn = fmaxf(v + h[idx], 0.f);
            h[idx] = hn;
            jk[idx] = fmaxf(jk[idx], hn);
            hs[r][c] = hn;
        } else hs[r][c] = 0.f;
    }
    __syncthreads();
    const int r = t >> 5;
    const int j = t & 31;
    const int n = n0 + r;
    float al = bl[j], ar = br[j];
#pragma unroll
    for (int c = 0; c < NC; ++c) {
        float hv = hs[r][c];
        al += hv * Wls[c * HC + j];
        ar += hv * Wrs[c * HC + j];
    }
    if (n < N_NODES) {
        xl[(size_t)n * HC + j] = f2bf(al);
        xr[(size_t)n * HC + j] = f2bf(ar);
    }
}

// ---- last layer: apply LN2, residual + relu, update h and jk-max -------------
__global__ __launch_bounds__(256) void k_final(
    const float* __restrict__ g2, const float* __restrict__ n2w,
    const float* __restrict__ n2b, const double* __restrict__ stats2,
    float* __restrict__ h, float* __restrict__ jk)
{
    const int i = blockIdx.x * 256 + threadIdx.x;
    if (i >= N_NODES * NC) return;
    const double cnt = (double)N_NODES * NC;
    const double mud = stats2[0] / cnt;
    const float mu  = (float)mud;
    const float var = (float)(stats2[1] / cnt - mud * mud);
    const float inv = rsqrtf(var + EPS);
    const int c = i & (NC - 1);
    float v = (g2[i] - mu) * inv * n2w[c] + n2b[c];
    float hn = fmaxf(v + h[i], 0.f);
    h[i] = hn;
    jk[i] = fmaxf(jk[i], hn);
}

extern "C" void kernel_launch(void* const* d_in, const int* in_sizes, int n_in,
                              void* d_out, int out_size, void* d_ws, size_t ws_size,
                              hipStream_t stream)
{
    const float* x     = (const float*)d_in[0];
    const int*   eidx  = (const int*)d_in[1];
    const float* eattr = (const float*)d_in[2];
    const float* embW  = (const float*)d_in[3];
    const float* embB  = (const float*)d_in[4];
    const float* ln0w  = (const float*)d_in[5];
    const float* ln0b  = (const float*)d_in[6];
    const float* Wl    = (const float*)d_in[7];
    const float* bl    = (const float*)d_in[8];
    const float* Wr    = (const float*)d_in[9];
    const float* br    = (const float*)d_in[10];
    const float* We    = (const float*)d_in[11];
    const float* att   = (const float*)d_in[12];
    const float* gatb  = (const float*)d_in[13];
    const float* n1w   = (const float*)d_in[14];
    const float* n1b   = (const float*)d_in[15];
    const float* linW  = (const float*)d_in[16];
    const float* linb  = (const float*)d_in[17];
    const float* n2w   = (const float*)d_in[18];
    const float* n2b   = (const float*)d_in[19];
    float* out = (float*)d_out;

    // ---- workspace layout ----
    char* ws = (char*)d_ws;
    double* stats = (double*)ws;                 // [0..1]=LN1, [2..3]=LN2
    char* p = ws + 1024;
    int* bcnt = (int*)p; p += 1024;              // 256 ints (zeroed)
    int* bbase = (int*)p; p += 4096;             // 257 ints
    int* bcur  = (int*)p; p += 1024;             // 256 ints
    int* offsets = (int*)p; p += (size_t)(N_NODES + 64) * 4;
    float* g = (float*)p; p += (size_t)N_NODES * HC * 4;
    int4* csr = (int4*)p; p += (size_t)N_EDGES * 16;
    // union: tmp_rec (CSR build only) <-> h/xl/xr/g2 (layers) — both 25.6 MB
    int4* tmp_rec = (int4*)p;
    char* q = p;
    p += (size_t)N_EDGES * 16;
    float* hq = (float*)q; q += (size_t)N_NODES * NC * 4;
    unsigned short* xlq = (unsigned short*)q; q += (size_t)N_NODES * HC * 2;
    unsigned short* xrq = (unsigned short*)q; q += (size_t)N_NODES * HC * 2;
    float* g2q = (float*)q;
    float2* part1 = (float2*)p; p += (size_t)MID_BLKS * 8;
    float2* part2 = (float2*)p; p += (size_t)MID_BLKS * 8;

    const int* srcp = eidx;
    const int* dstp = eidx + N_EDGES;

    // CSR build: bucket sort (stage-free pass1, bf16 eattr packed into 16B records)
    hipMemsetAsync(bcnt, 0, 1024, stream);
    k_bhist<<<P1_BLKS, 256, 0, stream>>>(dstp, bcnt);
    k_bscan<<<1, 256, 0, stream>>>(bcnt, bbase, bcur);
    k_pass1<<<P1_BLKS, 256, 0, stream>>>(srcp, dstp, (const float4*)eattr,
                                         bcur, tmp_rec);
    k_pass2<<<NBUCK, 512, 0, stream>>>(bbase, tmp_rec, offsets, csr);

    // embed + layer-0 transforms fused
    k_embed<<<(N_NODES + 15) / 16, 256, 0, stream>>>(
        x, embW, embB, ln0w, ln0b, Wl, bl, Wr, br, hq, out, xlq, xrq);

    // layer 0
    k_agg<<<AGG_BLKS, 256, 0, stream>>>(
        offsets, csr, We, att, gatb, xlq, xrq, g, part1);
    k_red<<<1, 256, 0, stream>>>(part1, AGG_BLKS, stats);
    k_mid<<<MID_BLKS, 256, 0, stream>>>(
        g, n1w, n1b, linW, linb, stats, g2q, part2);
    k_red<<<1, 256, 0, stream>>>(part2, MID_BLKS, stats + 2);
    k_ftrans<<<(N_NODES + 7) / 8, 256, 0, stream>>>(
        g2q, n2w, n2b, stats + 2, hq, out,
        Wl + NC * HC, bl + HC, Wr + NC * HC, br + HC, xlq, xrq);
    // layer 1
    k_agg<<<AGG_BLKS, 256, 0, stream>>>(
        offsets, csr, We + NED * HC, att + HC, gatb + HC, xlq, xrq, g, part1);
    k_red<<<1, 256, 0, stream>>>(part1, AGG_BLKS, stats);
    k_mid<<<MID_BLKS, 256, 0, stream>>>(
        g, n1w + HC, n1b + HC, linW + HC * NC, linb + NC, stats, g2q, part2);
    k_red<<<1, 256, 0, stream>>>(part2, MID_BLKS, stats + 2);
    k_final<<<(N_NODES * NC + 255) / 256, 256, 0, stream>>>(
        g2q, n2w + NC, n2b + NC, stats + 2, hq, out);
}

// Round 15
// 411.296 us; speedup vs baseline: 1.0310x; 1.0310x over previous
//
#include <hip/hip_runtime.h>

#define N_NODES 100000
#define N_EDGES 1600000
#define NF 128
#define NC 16
#define NH 2
#define HC 32   // NH*NC
#define NL 2
#define NED 4
#define EPS 1e-5f
#define NEG 0.2f
#define NBUCK 196                    // ceil(N_NODES / 512)
#define P1_CHUNK 4096
#define P1_BLKS ((N_EDGES + P1_CHUNK - 1) / P1_CHUNK)   // 391
#define AGG_BLKS ((N_NODES + 31) / 32)             // 3125  (32 dst/block, 8 lanes/dst)
#define MID_BLKS ((N_NODES + 15) / 16)             // 6250

typedef __attribute__((ext_vector_type(2))) float f32x2;

// ---- bf16 helpers (manual, RTN-even) -----------------------------------------
__device__ __forceinline__ unsigned short f2bf(float f) {
    unsigned int u = __float_as_uint(f);
    u += 0x7fffu + ((u >> 16) & 1u);
    return (unsigned short)(u >> 16);
}
__device__ __forceinline__ float bf2f(unsigned short u) {
    return __uint_as_float(((unsigned int)u) << 16);
}
__device__ __forceinline__ unsigned int pack_bf2(float a, float b) {
    return (unsigned int)f2bf(a) | ((unsigned int)f2bf(b) << 16);
}
__device__ __forceinline__ float bflo(int u) {
    return __uint_as_float(((unsigned int)u) << 16);
}
__device__ __forceinline__ float bfhi(int u) {
    return __uint_as_float(((unsigned int)u) & 0xffff0000u);
}
__device__ __forceinline__ f32x2 sp2(float v) { f32x2 r; r.x = v; r.y = v; return r; }
// 8-byte load helper: 4 adjacent bf16 channels (packed in int2) -> 2x f32x2
__device__ __forceinline__ void bf4_unpack(int2 v, f32x2& p01, f32x2& p23) {
    p01.x = bflo(v.x); p01.y = bfhi(v.x);
    p23.x = bflo(v.y); p23.y = bfhi(v.y);
}
__device__ __forceinline__ int2 ld8(const unsigned short* base, unsigned boff) {
    return *(const int2*)((const char*)base + boff);
}

// ---- embed + layer-0 transforms fused ----------------------------------------
// h = relu(node_LN(x @ W + b)); jk = h; xl/xr = bf16(h @ Wl + bl, h @ Wr + br)
__global__ __launch_bounds__(256) void k_embed(
    const float* __restrict__ x, const float* __restrict__ W,
    const float* __restrict__ b, const float* __restrict__ lnw,
    const float* __restrict__ lnb,
    const float* __restrict__ Wl, const float* __restrict__ bl,
    const float* __restrict__ Wr, const float* __restrict__ br,
    float* __restrict__ h, float* __restrict__ jk,
    unsigned short* __restrict__ xl, unsigned short* __restrict__ xr)
{
    __shared__ __align__(16) float WsT[NC][NF + 4];   // [c][f]
    __shared__ __align__(16) float xs[16][NF + 4];
    __shared__ float Wls[NC * HC], Wrs[NC * HC];
    __shared__ float hs16[16][NC + 1];
    const int t = threadIdx.x;
    for (int i = t; i < NF * NC; i += 256) {
        int f = i >> 4, c = i & 15;
        WsT[c][f] = W[i];
    }
    for (int i = t; i < NC * HC; i += 256) { Wls[i] = Wl[i]; Wrs[i] = Wr[i]; }
    const int n0 = blockIdx.x * 16;
    const float4* x4 = (const float4*)x;
    for (int i = t; i < 16 * (NF / 4); i += 256) {    // 512 float4
        int r = i >> 5, f4 = i & 31;
        int n = n0 + r;
        float4 v = (n < N_NODES) ? x4[(size_t)n * (NF / 4) + f4]
                                 : make_float4(0.f, 0.f, 0.f, 0.f);
        *(float4*)&xs[r][f4 * 4] = v;
    }
    __syncthreads();
    const int r = t >> 4;
    const int c = t & 15;
    const int n = n0 + r;
    float acc = b[c];
#pragma unroll
    for (int f4 = 0; f4 < NF / 4; ++f4) {
        float4 xv = *(const float4*)&xs[r][f4 * 4];
        float4 wv = *(const float4*)&WsT[c][f4 * 4];
        acc += xv.x * wv.x + xv.y * wv.y + xv.z * wv.z + xv.w * wv.w;
    }
    float s = acc;
    for (int m = 8; m >= 1; m >>= 1) s += __shfl_xor(s, m, 16);
    float mu = s * (1.f / 16.f);
    float d = acc - mu;
    float v = d * d;
    for (int m = 8; m >= 1; m >>= 1) v += __shfl_xor(v, m, 16);
    float inv = rsqrtf(v * (1.f / 16.f) + EPS);
    float out = fmaxf(d * inv * lnw[c] + lnb[c], 0.f);
    if (n < N_NODES) {
        h[(size_t)n * NC + c]  = out;
        jk[(size_t)n * NC + c] = out;
    }
    hs16[r][c] = (n < N_NODES) ? out : 0.f;
    __syncthreads();
    // layer-0 transforms: lane c covers channels j=c and j=c+16
    float al0 = bl[c], al1 = bl[c + 16];
    float ar0 = br[c], ar1 = br[c + 16];
#pragma unroll
    for (int cc = 0; cc < NC; ++cc) {
        float hv = hs16[r][cc];
        al0 += hv * Wls[cc * HC + c];      al1 += hv * Wls[cc * HC + c + 16];
        ar0 += hv * Wrs[cc * HC + c];      ar1 += hv * Wrs[cc * HC + c + 16];
    }
    if (n < N_NODES) {
        xl[(size_t)n * HC + c]      = f2bf(al0);
        xl[(size_t)n * HC + c + 16] = f2bf(al1);
        xr[(size_t)n * HC + c]      = f2bf(ar0);
        xr[(size_t)n * HC + c + 16] = f2bf(ar1);
    }
}

// ---- bucket histogram (bucket = dst >> 9), LDS-staged ------------------------
__global__ __launch_bounds__(256) void k_bhist(
    const int* __restrict__ dst, int* __restrict__ bcnt)
{
    __shared__ int hist[256];
    const int t = threadIdx.x;
    hist[t] = 0;
    __syncthreads();
    const int e0 = blockIdx.x * P1_CHUNK;
    const int cnt = min(P1_CHUNK, N_EDGES - e0);
    for (int i = t; i < cnt; i += 256)
        atomicAdd(&hist[dst[e0 + i] >> 9], 1);
    __syncthreads();
    if (hist[t] > 0) atomicAdd(&bcnt[t], hist[t]);
}

// ---- scan 196 bucket counts -> bases + working cursors -----------------------
__global__ __launch_bounds__(256) void k_bscan(
    const int* __restrict__ bcnt, int* __restrict__ bbase, int* __restrict__ bcur)
{
    __shared__ int tmp[256];
    const int t = threadIdx.x;
    int v0 = bcnt[t];
    tmp[t] = v0;
    __syncthreads();
    for (int off = 1; off < 256; off <<= 1) {
        int v = (t >= off) ? tmp[t - off] : 0;
        __syncthreads();
        tmp[t] += v;
        __syncthreads();
    }
    int excl = tmp[t] - v0;
    bbase[t] = excl;
    bcur[t]  = excl;
    if (t == 255) bbase[256] = tmp[t];   // == N_EDGES
}

// ---- pass1: no staging, no scan (chunk 4096 = measured optimum) --------------
__global__ __launch_bounds__(256) void k_pass1(
    const int* __restrict__ src, const int* __restrict__ dst,
    const float4* __restrict__ ea4, int* __restrict__ bcur,
    int4* __restrict__ tmp_rec)
{
    __shared__ int hist[256];
    __shared__ int gbase[256];
    __shared__ int lcur[256];
    const int t = threadIdx.x;
    const int e0 = blockIdx.x * P1_CHUNK;
    const int cnt = min(P1_CHUNK, N_EDGES - e0);
    hist[t] = 0; lcur[t] = 0;
    __syncthreads();
    for (int i = t; i < cnt; i += 256)
        atomicAdd(&hist[dst[e0 + i] >> 9], 1);
    __syncthreads();
    {
        int c = hist[t];
        gbase[t] = (c > 0) ? atomicAdd(&bcur[t], c) : 0;
    }
    __syncthreads();
    for (int i = t; i < cnt; i += 256) {
        int e = e0 + i;
        int d = dst[e];                 // second read: 16KB window, L1 hit
        int s = src[e];
        float4 ea = ea4[e];
        int b = d >> 9;
        int lpos = atomicAdd(&lcur[b], 1);
        tmp_rec[gbase[b] + lpos] = make_int4(s, d,
                                             (int)pack_bf2(ea.x, ea.y),
                                             (int)pack_bf2(ea.z, ea.w));
    }
}

// ---- pass2: one 512-thread block per bucket; per-dst hist+scan -> CSR --------
__global__ __launch_bounds__(512) void k_pass2(
    const int* __restrict__ bbase, const int4* __restrict__ tmp_rec,
    int* __restrict__ offsets, int4* __restrict__ csr)
{
    __shared__ int hist[512];
    __shared__ int cur[512];
    __shared__ int scanbuf[256];
    const int b = blockIdx.x, t = threadIdx.x;
    const int ebeg = bbase[b], eend = bbase[b + 1];
    hist[t] = 0;
    __syncthreads();
    for (int i = ebeg + t; i < eend; i += 512)
        atomicAdd(&hist[tmp_rec[i].y & 511], 1);
    __syncthreads();
    int a0 = 0, a1 = 0, pair = 0;
    if (t < 256) {
        a0 = hist[2 * t]; a1 = hist[2 * t + 1];
        pair = a0 + a1;
        scanbuf[t] = pair;
    }
    __syncthreads();
    for (int off = 1; off < 256; off <<= 1) {
        int v = (t < 256 && t >= off) ? scanbuf[t - off] : 0;
        __syncthreads();
        if (t < 256) scanbuf[t] += v;
        __syncthreads();
    }
    if (t < 256) {
        int ex2 = scanbuf[t] - pair;
        cur[2 * t]     = ex2;
        cur[2 * t + 1] = ex2 + a0;
    }
    __syncthreads();
    {
        int n = b * 512 + t;
        if (n < N_NODES) offsets[n] = ebeg + cur[t];
        if (b == NBUCK - 1 && t == 0) offsets[N_NODES] = N_EDGES;
    }
    __syncthreads();
    // permute (writes stay inside this bucket's L2-resident window)
    for (int i = ebeg + t; i < eend; i += 512) {
        int4 rec = tmp_rec[i];
        int pos = ebeg + atomicAdd(&cur[rec.y & 511], 1);
        csr[pos] = rec;   // {src, d(unused later), eab01, eab23}
    }
}

// per-edge compute macro pieces for k_agg (8 lanes/dst, 4 channels/lane)
#define EDGE_MSG(RA, RB, RZ, RW)                                              \
    RA += sp2(bflo(RZ)) * w0a; RB += sp2(bflo(RZ)) * w0b;                     \
    RA += sp2(bfhi(RZ)) * w1a; RB += sp2(bfhi(RZ)) * w1b;                     \
    RA += sp2(bflo(RW)) * w2a; RB += sp2(bflo(RW)) * w2b;                     \
    RA += sp2(bfhi(RW)) * w3a; RB += sp2(bfhi(RW)) * w3b;                     \
    RA.x = fmaxf(RA.x, NEG * RA.x); RA.y = fmaxf(RA.y, NEG * RA.y);           \
    RB.x = fmaxf(RB.x, NEG * RB.x); RB.y = fmaxf(RB.y, NEG * RB.y);

// ---- aggregation: 8 lanes/dst, 4 channels/lane, unroll-4 (R10-proven) --------
__global__ __launch_bounds__(256) void k_agg(
    const int* __restrict__ offsets, const int4* __restrict__ csr,
    const float* __restrict__ We, const float* __restrict__ att,
    const float* __restrict__ gat_b,
    const unsigned short* __restrict__ xl, const unsigned short* __restrict__ xr,
    float* __restrict__ g, float2* __restrict__ part)
{
    __shared__ float Wes[NED * HC];
    __shared__ float atts[HC], gbs[HC];
    const int t = threadIdx.x;
    if (t < NED * HC) Wes[t] = We[t];
    if (t < HC) { atts[t] = att[t]; gbs[t] = gat_b[t]; }
    __syncthreads();
    const int grp = t >> 3;          // 32 groups of 8 lanes
    const int l   = t & 7;           // channels 4l..4l+3 ; head = l>>2
    const int d = blockIdx.x * 32 + grp;
    f32x2 gv01 = sp2(0.f), gv23 = sp2(0.f);
    if (d < N_NODES) {
        const int c0 = l << 2;
        f32x2 a01; a01.x = atts[c0];     a01.y = atts[c0 + 1];
        f32x2 a23; a23.x = atts[c0 + 2]; a23.y = atts[c0 + 3];
        f32x2 w0a, w0b, w1a, w1b, w2a, w2b, w3a, w3b;
        w0a.x = Wes[c0];          w0a.y = Wes[c0 + 1];
        w0b.x = Wes[c0 + 2];      w0b.y = Wes[c0 + 3];
        w1a.x = Wes[HC + c0];     w1a.y = Wes[HC + c0 + 1];
        w1b.x = Wes[HC + c0 + 2]; w1b.y = Wes[HC + c0 + 3];
        w2a.x = Wes[2 * HC + c0];     w2a.y = Wes[2 * HC + c0 + 1];
        w2b.x = Wes[2 * HC + c0 + 2]; w2b.y = Wes[2 * HC + c0 + 3];
        w3a.x = Wes[3 * HC + c0];     w3a.y = Wes[3 * HC + c0 + 1];
        w3b.x = Wes[3 * HC + c0 + 2]; w3b.y = Wes[3 * HC + c0 + 3];
        const unsigned jb = (unsigned)(l << 3);     // byte offset of channel quad
        f32x2 xld01, xld23, xrd01, xrd23;
        bf4_unpack(ld8(xl, ((unsigned)d << 6) + jb), xld01, xld23);
        bf4_unpack(ld8(xr, ((unsigned)d << 6) + jb), xrd01, xrd23);
        // self-loop (ew = 0); logits tiny: exp without segment-max is exact enough
        f32x2 m01 = xld01 + xrd01, m23 = xld23 + xrd23;
        m01.x = fmaxf(m01.x, NEG * m01.x); m01.y = fmaxf(m01.y, NEG * m01.y);
        m23.x = fmaxf(m23.x, NEG * m23.x); m23.y = fmaxf(m23.y, NEG * m23.y);
        float p = m01.x * a01.x + m01.y * a01.y + m23.x * a23.x + m23.y * a23.y;
        p += __shfl_xor(p, 1);           // quad-perm DPP
        p += __shfl_xor(p, 2);           // quad-perm DPP
        float eh = __expf(p);
        f32x2 acc01 = sp2(eh) * xld01, acc23 = sp2(eh) * xld23;
        float den = eh;
        const int base = offsets[d];
        const int deg  = offsets[d + 1] - base;
        int k = 0;
        for (; k + 4 <= deg; k += 4) {
            const int b0 = base + k;
            const int4 r0 = csr[b0],     r1 = csr[b0 + 1];
            const int4 r2 = csr[b0 + 2], r3 = csr[b0 + 3];
            const int2 v0 = ld8(xl, ((unsigned)r0.x << 6) + jb);
            const int2 v1 = ld8(xl, ((unsigned)r1.x << 6) + jb);
            const int2 v2 = ld8(xl, ((unsigned)r2.x << 6) + jb);
            const int2 v3 = ld8(xl, ((unsigned)r3.x << 6) + jb);
            f32x2 x0a, x0b, x1a, x1b, x2a, x2b, x3a, x3b;
            bf4_unpack(v0, x0a, x0b); bf4_unpack(v1, x1a, x1b);
            bf4_unpack(v2, x2a, x2b); bf4_unpack(v3, x3a, x3b);
            f32x2 m0a = x0a + xrd01, m0b = x0b + xrd23;
            f32x2 m1a = x1a + xrd01, m1b = x1b + xrd23;
            f32x2 m2a = x2a + xrd01, m2b = x2b + xrd23;
            f32x2 m3a = x3a + xrd01, m3b = x3b + xrd23;
            EDGE_MSG(m0a, m0b, r0.z, r0.w)
            EDGE_MSG(m1a, m1b, r1.z, r1.w)
            EDGE_MSG(m2a, m2b, r2.z, r2.w)
            EDGE_MSG(m3a, m3b, r3.z, r3.w)
            float p0 = m0a.x * a01.x + m0a.y * a01.y + m0b.x * a23.x + m0b.y * a23.y;
            float p1 = m1a.x * a01.x + m1a.y * a01.y + m1b.x * a23.x + m1b.y * a23.y;
            float p2 = m2a.x * a01.x + m2a.y * a01.y + m2b.x * a23.x + m2b.y * a23.y;
            float p3 = m3a.x * a01.x + m3a.y * a01.y + m3b.x * a23.x + m3b.y * a23.y;
            p0 += __shfl_xor(p0, 1); p1 += __shfl_xor(p1, 1);
            p2 += __shfl_xor(p2, 1); p3 += __shfl_xor(p3, 1);
            p0 += __shfl_xor(p0, 2); p1 += __shfl_xor(p1, 2);
            p2 += __shfl_xor(p2, 2); p3 += __shfl_xor(p3, 2);
            const float ee0 = __expf(p0), ee1 = __expf(p1);
            const float ee2 = __expf(p2), ee3 = __expf(p3);
            acc01 += sp2(ee0) * x0a; acc23 += sp2(ee0) * x0b;
            acc01 += sp2(ee1) * x1a; acc23 += sp2(ee1) * x1b;
            acc01 += sp2(ee2) * x2a; acc23 += sp2(ee2) * x2b;
            acc01 += sp2(ee3) * x3a; acc23 += sp2(ee3) * x3b;
            den += ee0 + ee1 + ee2 + ee3;
        }
        for (; k < deg; ++k) {
            const int4 r = csr[base + k];
            f32x2 xa, xb;
            bf4_unpack(ld8(xl, ((unsigned)r.x << 6) + jb), xa, xb);
            f32x2 ma = xa + xrd01, mb = xb + xrd23;
            EDGE_MSG(ma, mb, r.z, r.w)
            float p = ma.x * a01.x + ma.y * a01.y + mb.x * a23.x + mb.y * a23.y;
            p += __shfl_xor(p, 1);
            p += __shfl_xor(p, 2);
            const float ee = __expf(p);
            acc01 += sp2(ee) * xa; acc23 += sp2(ee) * xb;
            den += ee;
        }
        const float invd = 1.f / den;
        gv01.x = acc01.x * invd + gbs[c0];
        gv01.y = acc01.y * invd + gbs[c0 + 1];
        gv23.x = acc23.x * invd + gbs[c0 + 2];
        gv23.y = acc23.y * invd + gbs[c0 + 3];
        float4 wv; wv.x = gv01.x; wv.y = gv01.y; wv.z = gv23.x; wv.w = gv23.y;
        *(float4*)&g[(size_t)d * HC + c0] = wv;
    }
    float s  = gv01.x + gv01.y + gv23.x + gv23.y;
    float ss = gv01.x * gv01.x + gv01.y * gv01.y + gv23.x * gv23.x + gv23.y * gv23.y;
    for (int m = 32; m >= 1; m >>= 1) { s += __shfl_xor(s, m); ss += __shfl_xor(ss, m); }
    __shared__ float sr[4], ssr[4];
    const int w = t >> 6;
    if ((t & 63) == 0) { sr[w] = s; ssr[w] = ss; }
    __syncthreads();
    if (t == 0) part[blockIdx.x] = make_float2(sr[0] + sr[1] + sr[2] + sr[3],
                                               ssr[0] + ssr[1] + ssr[2] + ssr[3]);
}

// ---- reduce block partials -> stats[0..1] ------------------------------------
__global__ __launch_bounds__(256) void k_red(
    const float2* __restrict__ part, int n, double* __restrict__ out)
{
    const int t = threadIdx.x;
    double s = 0.0, ss = 0.0;
    for (int i = t; i < n; i += 256) {
        float2 p = part[i];
        s += (double)p.x; ss += (double)p.y;
    }
    for (int m = 32; m >= 1; m >>= 1) { s += __shfl_xor(s, m); ss += __shfl_xor(ss, m); }
    __shared__ double sr[4], ssr[4];
    const int w = t >> 6;
    if ((t & 63) == 0) { sr[w] = s; ssr[w] = ss; }
    __syncthreads();
    if (t == 0) {
        out[0] = sr[0] + sr[1] + sr[2] + sr[3];
        out[1] = ssr[0] + ssr[1] + ssr[2] + ssr[3];
    }
}

// ---- apply LN1 + relu + linear(32->16) + partial stats for LN2 ---------------
__global__ __launch_bounds__(256) void k_mid(
    const float* __restrict__ g,
    const float* __restrict__ n1w, const float* __restrict__ n1b,
    const float* __restrict__ linW, const float* __restrict__ linb,
    const double* __restrict__ stats1, float* __restrict__ g2,
    float2* __restrict__ part)
{
    __shared__ float Ws[HC * NC];
    __shared__ float rs[16][HC + 1];
    const int t = threadIdx.x;
    for (int i = t; i < HC * NC; i += 256) Ws[i] = linW[i];
    const double cnt = (double)N_NODES * HC;
    const double mud = stats1[0] / cnt;
    const float mu  = (float)mud;
    const float var = (float)(stats1[1] / cnt - mud * mud);
    const float inv = rsqrtf(var + EPS);
    const int n0 = blockIdx.x * 16;
    for (int i = t; i < 16 * HC; i += 256) {
        int r = i >> 5, j = i & 31;
        int n = n0 + r;
        float v = (n < N_NODES) ? g[(size_t)n * HC + j] : mu;
        v = (v - mu) * inv * n1w[j] + n1b[j];
        rs[r][j] = fmaxf(v, 0.f);
    }
    __syncthreads();
    const int r = t >> 4, c = t & 15;
    const int n = n0 + r;
    float acc = linb[c];
#pragma unroll
    for (int j = 0; j < HC; ++j) acc += rs[r][j] * Ws[j * NC + c];
    float val = (n < N_NODES) ? acc : 0.f;
    if (n < N_NODES) g2[(size_t)n * NC + c] = acc;
    float s = val, ss = val * val;
    for (int m = 32; m >= 1; m >>= 1) { s += __shfl_xor(s, m); ss += __shfl_xor(ss, m); }
    __shared__ float sr[4], ssr[4];
    const int w = t >> 6;
    if ((t & 63) == 0) { sr[w] = s; ssr[w] = ss; }
    __syncthreads();
    if (t == 0) part[blockIdx.x] = make_float2(sr[0] + sr[1] + sr[2] + sr[3],
                                               ssr[0] + ssr[1] + ssr[2] + ssr[3]);
}

// ---- fused: apply LN2 + residual + relu + jk-max, then next-layer transforms -
__global__ __launch_bounds__(256) void k_ftrans(
    const float* __restrict__ g2, const float* __restrict__ n2w,
    const float* __restrict__ n2b, const double* __restrict__ stats2,
    float* __restrict__ h, float* __restrict__ jk,
    const float* __restrict__ Wl, const float* __restrict__ bl,
    const float* __restrict__ Wr, const float* __restrict__ br,
    unsigned short* __restrict__ xl, unsigned short* __restrict__ xr)
{
    __shared__ float Wls[NC * HC], Wrs[NC * HC];
    __shared__ float hs[8][NC + 1];
    const int t = threadIdx.x;
    for (int i = t; i < NC * HC; i += 256) { Wls[i] = Wl[i]; Wrs[i] = Wr[i]; }
    const double cnt = (double)N_NODES * NC;
    const double mud = stats2[0] / cnt;
    const float mu  = (float)mud;
    const float var = (float)(stats2[1] / cnt - mud * mud);
    const float inv = rsqrtf(var + EPS);
    const int n0 = blockIdx.x * 8;
    if (t < 8 * NC) {
        int r = t >> 4, c = t & 15;
        int n = n0 + r;
        if (n < N_NODES) {
            size_t idx = (size_t)n * NC + c;
            float v = (g2[idx] - mu) * inv * n2w[c] + n2b[c];
            float hn = fmaxf(v + h[idx], 0.f);
            h[idx] = hn;
            jk[idx] = fmaxf(jk[idx], hn);
            hs[r][c] = hn;
        } else hs[r][c] = 0.f;
    }
    __syncthreads();
    const int r = t >> 5;
    const int j = t & 31;
    const int n = n0 + r;
    float al = bl[j], ar = br[j];
#pragma unroll
    for (int c = 0; c < NC; ++c) {
        float hv = hs[r][c];
        al += hv * Wls[c * HC + j];
        ar += hv * Wrs[c * HC + j];
    }
    if (n < N_NODES) {
        xl[(size_t)n * HC + j] = f2bf(al);
        xr[(size_t)n * HC + j] = f2bf(ar);
    }
}

// ---- last layer: apply LN2, residual + relu, update h and jk-max -------------
__global__ __launch_bounds__(256) void k_final(
    const float* __restrict__ g2, const float* __restrict__ n2w,
    const float* __restrict__ n2b, const double* __restrict__ stats2,
    float* __restrict__ h, float* __restrict__ jk)
{
    const int i = blockIdx.x * 256 + threadIdx.x;
    if (i >= N_NODES * NC) return;
    const double cnt = (double)N_NODES * NC;
    const double mud = stats2[0] / cnt;
    const float mu  = (float)mud;
    const float var = (float)(stats2[1] / cnt - mud * mud);
    const float inv = rsqrtf(var + EPS);
    const int c = i & (NC - 1);
    float v = (g2[i] - mu) * inv * n2w[c] + n2b[c];
    float hn = fmaxf(v + h[i], 0.f);
    h[i] = hn;
    jk[i] = fmaxf(jk[i], hn);
}

extern "C" void kernel_launch(void* const* d_in, const int* in_sizes, int n_in,
                              void* d_out, int out_size, void* d_ws, size_t ws_size,
                              hipStream_t stream)
{
    const float* x     = (const float*)d_in[0];
    const int*   eidx  = (const int*)d_in[1];
    const float* eattr = (const float*)d_in[2];
    const float* embW  = (const float*)d_in[3];
    const float* embB  = (const float*)d_in[4];
    const float* ln0w  = (const float*)d_in[5];
    const float* ln0b  = (const float*)d_in[6];
    const float* Wl    = (const float*)d_in[7];
    const float* bl    = (const float*)d_in[8];
    const float* Wr    = (const float*)d_in[9];
    const float* br    = (const float*)d_in[10];
    const float* We    = (const float*)d_in[11];
    const float* att   = (const float*)d_in[12];
    const float* gatb  = (const float*)d_in[13];
    const float* n1w   = (const float*)d_in[14];
    const float* n1b   = (const float*)d_in[15];
    const float* linW  = (const float*)d_in[16];
    const float* linb  = (const float*)d_in[17];
    const float* n2w   = (const float*)d_in[18];
    const float* n2b   = (const float*)d_in[19];
    float* out = (float*)d_out;

    // ---- workspace layout ----
    char* ws = (char*)d_ws;
    double* stats = (double*)ws;                 // [0..1]=LN1, [2..3]=LN2
    char* p = ws + 1024;
    int* bcnt = (int*)p; p += 1024;              // 256 ints (zeroed)
    int* bbase = (int*)p; p += 4096;             // 257 ints
    int* bcur  = (int*)p; p += 1024;             // 256 ints
    int* offsets = (int*)p; p += (size_t)(N_NODES + 64) * 4;
    float* g = (float*)p; p += (size_t)N_NODES * HC * 4;
    int4* csr = (int4*)p; p += (size_t)N_EDGES * 16;
    // union: tmp_rec (CSR build only) <-> h/xl/xr/g2 (layers) — both 25.6 MB
    int4* tmp_rec = (int4*)p;
    char* q = p;
    p += (size_t)N_EDGES * 16;
    float* hq = (float*)q; q += (size_t)N_NODES * NC * 4;
    unsigned short* xlq = (unsigned short*)q; q += (size_t)N_NODES * HC * 2;
    unsigned short* xrq = (unsigned short*)q; q += (size_t)N_NODES * HC * 2;
    float* g2q = (float*)q;
    float2* part1 = (float2*)p; p += (size_t)MID_BLKS * 8;
    float2* part2 = (float2*)p; p += (size_t)MID_BLKS * 8;

    const int* srcp = eidx;
    const int* dstp = eidx + N_EDGES;

    // CSR build: bucket sort (stage-free pass1, bf16 eattr packed into 16B records)
    hipMemsetAsync(bcnt, 0, 1024, stream);
    k_bhist<<<P1_BLKS, 256, 0, stream>>>(dstp, bcnt);
    k_bscan<<<1, 256, 0, stream>>>(bcnt, bbase, bcur);
    k_pass1<<<P1_BLKS, 256, 0, stream>>>(srcp, dstp, (const float4*)eattr,
                                         bcur, tmp_rec);
    k_pass2<<<NBUCK, 512, 0, stream>>>(bbase, tmp_rec, offsets, csr);

    // embed + layer-0 transforms fused
    k_embed<<<(N_NODES + 15) / 16, 256, 0, stream>>>(
        x, embW, embB, ln0w, ln0b, Wl, bl, Wr, br, hq, out, xlq, xrq);

    // layer 0
    k_agg<<<AGG_BLKS, 256, 0, stream>>>(
        offsets, csr, We, att, gatb, xlq, xrq, g, part1);
    k_red<<<1, 256, 0, stream>>>(part1, AGG_BLKS, stats);
    k_mid<<<MID_BLKS, 256, 0, stream>>>(
        g, n1w, n1b, linW, linb, stats, g2q, part2);
    k_red<<<1, 256, 0, stream>>>(part2, MID_BLKS, stats + 2);
    k_ftrans<<<(N_NODES + 7) / 8, 256, 0, stream>>>(
        g2q, n2w, n2b, stats + 2, hq, out,
        Wl + NC * HC, bl + HC, Wr + NC * HC, br + HC, xlq, xrq);
    // layer 1
    k_agg<<<AGG_BLKS, 256, 0, stream>>>(
        offsets, csr, We + NED * HC, att + HC, gatb + HC, xlq, xrq, g, part1);
    k_red<<<1, 256, 0, stream>>>(part1, AGG_BLKS, stats);
    k_mid<<<MID_BLKS, 256, 0, stream>>>(
        g, n1w + HC, n1b + HC, linW + HC * NC, linb + NC, stats, g2q, part2);
    k_red<<<1, 256, 0, stream>>>(part2, MID_BLKS, stats + 2);
    k_final<<<(N_NODES * NC + 255) / 256, 256, 0, stream>>>(
        g2q, n2w + NC, n2b + NC, stats + 2, hq, out);
}